// Round 13
// baseline (98.513 us; speedup 1.0000x reference)
//
#include <hip/hip_runtime.h>
#include <cstdint>
#include <cstddef>

// ---------------- problem constants ----------------
#define NB    32          // batch
#define CI    128         // in channels
#define CO    256         // out channels
#define HW_   56          // spatial
#define HP    58          // padded spatial
#define KTOT  1152        // 128*9 reduction
#define NKT   36          // K-tiles of 32
#define MTOT  (NB * HW_ * HW_)   // 100352 output pixels

static constexpr size_t XP_ELEMS = (size_t)NB * HP * HP * CI;   // 13,776,896
static constexpr size_t WT_ELEMS = (size_t)CO * KTOT;           // 294,912
static constexpr size_t XP_BYTES = XP_ELEMS * 2;
static constexpr size_t WT_BYTES = WT_ELEMS * 2;

typedef __attribute__((ext_vector_type(8))) short bf16x8;
typedef __attribute__((ext_vector_type(4))) float f32x4;

__device__ __forceinline__ short f32_to_bf16(float f) {
  uint32_t u = __float_as_uint(f);
  uint32_t r = (u + 0x7FFFu + ((u >> 16) & 1u)) >> 16;
  return (short)r;
}

typedef __attribute__((address_space(3))) void       lds_void;
typedef const __attribute__((address_space(1))) void gbl_void;

__device__ __forceinline__ void gload16(const void* g, void* l) {
  // dest = wave-uniform LDS base; HW writes lane's 16B at base + lane*16
  __builtin_amdgcn_global_load_lds((gbl_void*)g, (lds_void*)l, 16, 0, 0);
}

// ---- pre-pass: x NCHW f32 -> padded NHWC bf16; wt OIHW -> [o][kh][kw][c] bf16 ----
// (verified-correct R4/R12 version)
__global__ void pad_convert(const float* __restrict__ x, short* __restrict__ xp,
                            const float* __restrict__ wt, short* __restrict__ wbT) {
  __shared__ float lds[CI][57];
  const int blk = blockIdx.x;    // NB*HP = 1856
  const int hp  = blk % HP;
  const int nb  = blk / HP;
  const int tid = threadIdx.x;   // 256

  if (blk < 1152) {              // 1152*256 == WT_ELEMS (scalar per thread)
    int idx = blk * 256 + tid;
    int c  = idx & 127;
    int t  = idx >> 7;          // o*9 + kh*3 + kw
    int kw = t % 3;  int t2 = t / 3;
    int kh = t2 % 3; int o  = t2 / 3;
    wbT[idx] = f32_to_bf16(wt[(((size_t)o * CI + c) * 3 + kh) * 3 + kw]);
  }

  const bool interior = (hp >= 1 && hp <= HW_);
  if (interior) {
    const float* src = x + (size_t)nb * CI * HW_ * HW_ + (size_t)(hp - 1) * HW_;
    for (int t = tid; t < CI * HW_; t += 256) {
      int c = t / HW_, w = t - (t / HW_) * HW_;
      lds[c][w] = src[(size_t)c * HW_ * HW_ + w];
    }
  }
  __syncthreads();
  short* dst = xp + (size_t)(nb * HP + hp) * HP * CI;
  for (int t = tid; t < HP * CI / 4; t += 256) {
    const int wp = t >> 5;
    const int c4 = (t & 31) * 4;
    short4 s;
    if (interior && wp >= 1 && wp <= HW_) {
      s.x = f32_to_bf16(lds[c4 + 0][wp - 1]);
      s.y = f32_to_bf16(lds[c4 + 1][wp - 1]);
      s.z = f32_to_bf16(lds[c4 + 2][wp - 1]);
      s.w = f32_to_bf16(lds[c4 + 3][wp - 1]);
    } else {
      s.x = s.y = s.z = s.w = 0;
    }
    *(short4*)(dst + t * 4) = s;
  }
}

// scalar byte offset into an xp pixel row for K-tile u (tap + channel-quarter)
__device__ __forceinline__ int stage_aoff(int u) {
  const int tap = u >> 2;            // 0..8
  const int cq  = u & 3;             // channel quarter (32 ch)
  const int kh  = tap / 3, kw = tap - kh * 3;
  return ((kh * HP + kw) * CI + cq * 32) * 2;
}

// ---------------- main: implicit GEMM, 128x128 tile, BK=32, 4 waves ----------------
// R13 = R4's proven ledger/swizzle at m97's 128x128 geometry:
//  * per-wave 64x64 (4x4 frags, acc = 64 VGPR -> ~120 total, 3 waves/SIMD OK)
//  * 3 buffers x 16KB (A 8K + B 8K) = 48KB -> 3 blocks/CU (12 waves: in-round
//    LDS cap ~45% vs R4's ~38%, and grid 1568 -> 3.06 rounds -> tail eff 97%
//    vs R4's 0.766)
//  * STAGE = 4 gloads/thread; stage-ahead 2; boundary vmcnt(4) confirms tile
//    v+1 (its 4 loads are the only ones older than the 4 just issued);
//    vmcnt(0) only at v=NKT-2. Ledger identical to R4 (passed 2 rounds).
//  * swizzle pcs/koff verbatim from R4 (0 bank conflicts, 4 passing rounds).
__global__ __launch_bounds__(256, 3) void conv_gemm(
    const short* __restrict__ xp, const short* __restrict__ wbT,
    const float* __restrict__ bias, float* __restrict__ out) {
  __shared__ __align__(16) char lds_[3 * 16384];

  const int tid = threadIdx.x;     // 256
  const int l   = tid & 63;
  const int wv  = tid >> 6;        // 0..3
  const int wm  = wv >> 1;         // 0..1  (m half: 64 rows)
  const int wn  = wv & 1;          // 0..1  (oc half: 64 cols)

  // grid 1568 = 8 XCDs x 196; chunked bijective swizzle, nt inner (A L2 reuse)
  const int bid = blockIdx.x;
  const int lin = (bid & 7) * 196 + (bid >> 3);
  const int mt  = lin >> 1;        // 0..783
  const int nt  = lin & 1;

  // ---- staging source pointers (pre-swizzled per rule #21; R4 verbatim) ----
  // gload g covers rows 64g + 16wv + (l>>2); lane piece (l&3); src piece ^((l>>3)&3)
  const int pcs  = (((l & 3) ^ ((l >> 3) & 3)) << 4);
  const int srow = 16 * wv + (l >> 2);                 // 0..63 per gload group
  const char *aSrc0, *aSrc1;
  {
#pragma unroll
    for (int g = 0; g < 2; ++g) {
      int m  = mt * 128 + 64 * g + srow;
      int nb = m / 3136, hw = m - nb * 3136;
      int h = hw / HW_, w = hw - (hw / HW_) * HW_;
      const char* p = (const char*)xp + ((size_t)((nb * HP + h) * HP + w) * CI) * 2 + pcs;
      if (g == 0) aSrc0 = p; else aSrc1 = p;
    }
  }
  const char* bSrc0 = (const char*)wbT + (size_t)(nt * 128 +      srow) * KTOT * 2 + pcs;
  const char* bSrc1 = (const char*)wbT + (size_t)(nt * 128 + 64 + srow) * KTOT * 2 + pcs;

  // ---- frag read lane offsets (swizzled koff; R4 verbatim, 0 conflicts) ----
  const int lm   = l & 15;
  const int koff = (((l >> 4) ^ ((l >> 1) & 3)) << 4);
  const int raOff = (wm * 64 + lm) * 64 + koff;   // + g*1024, g=0..3
  const int rbOff = (wn * 64 + lm) * 64 + koff;   // + h*1024 (B region +8192)

  char* B0 = lds_;
  char* B1 = lds_ + 16384;
  char* B2 = lds_ + 32768;

#define STAGE(U, BUF)                                                        \
  {                                                                          \
    const int ao_ = stage_aoff(U);                                           \
    const int bo_ = (U) * 64;                                                \
    gload16(aSrc0 + ao_, (BUF) +         wv * 1024);                         \
    gload16(aSrc1 + ao_, (BUF) +  4096 + wv * 1024);                         \
    gload16(bSrc0 + bo_, (BUF) +  8192 + wv * 1024);                         \
    gload16(bSrc1 + bo_, (BUF) + 12288 + wv * 1024);                         \
  }

  f32x4 acc[4][4];
#pragma unroll
  for (int g = 0; g < 4; ++g)
#pragma unroll
    for (int h = 0; h < 4; ++h) acc[g][h] = {0.f, 0.f, 0.f, 0.f};

  // ---- prologue: stage tiles 0,1; confirm tile 0 (leave tile 1's 4) ----
  STAGE(0, B0)
  STAGE(1, B1)
  asm volatile("s_waitcnt vmcnt(4)" ::: "memory");
  __builtin_amdgcn_s_barrier();
  __builtin_amdgcn_sched_barrier(0);

#define TILE_BODY(V, CUR, STG)                                               \
  {                                                                          \
    const int v_ = (V);                                                      \
    if (v_ + 2 < NKT) STAGE(v_ + 2, STG)                                     \
    bf16x8 af[4], bf[4];                                                     \
    _Pragma("unroll") for (int g = 0; g < 4; ++g)                            \
        af[g] = *(const bf16x8*)((CUR) + raOff + g * 1024);                  \
    _Pragma("unroll") for (int h = 0; h < 4; ++h)                            \
        bf[h] = *(const bf16x8*)((CUR) + 8192 + rbOff + h * 1024);           \
    __builtin_amdgcn_s_setprio(1);                                           \
    _Pragma("unroll") for (int g = 0; g < 4; ++g)                            \
      _Pragma("unroll") for (int h = 0; h < 4; ++h)                          \
        acc[g][h] = __builtin_amdgcn_mfma_f32_16x16x32_bf16(                 \
            bf[h], af[g], acc[g][h], 0, 0, 0);                               \
    __builtin_amdgcn_s_setprio(0);                                           \
    if (v_ < NKT - 1) {                                                      \
      if (v_ == NKT - 2) { asm volatile("s_waitcnt vmcnt(0)" ::: "memory"); }\
      else               { asm volatile("s_waitcnt vmcnt(4)" ::: "memory"); }\
      __builtin_amdgcn_s_barrier();                                          \
      __builtin_amdgcn_sched_barrier(0);                                     \
    }                                                                        \
  }

  for (int v3 = 0; v3 < NKT; v3 += 3) {
    TILE_BODY(v3 + 0, B0, B2)   // tile v reads buf v%3, stages v+2 into (v+2)%3
    TILE_BODY(v3 + 1, B1, B0)
    TILE_BODY(v3 + 2, B2, B1)
  }
#undef TILE_BODY
#undef STAGE

  // ---- epilogue: D rows = oc, cols = m (swapped operands) -> coalesced stores ----
  const int mBase = mt * 128 + wm * 64 + lm;
  const int ocB   = nt * 128 + wn * 64 + (l >> 4) * 4;
  float bv[4][4];
#pragma unroll
  for (int h = 0; h < 4; ++h)
#pragma unroll
    for (int j = 0; j < 4; ++j) bv[h][j] = bias[ocB + h * 16 + j];
#pragma unroll
  for (int g = 0; g < 4; ++g) {
    const int m  = mBase + g * 16;
    const int nb = m / 3136;
    const int hw = m - nb * 3136;
    float* op = out + (size_t)nb * CO * 3136 + hw;
#pragma unroll
    for (int h = 0; h < 4; ++h) {
      const int oc = ocB + h * 16;
#pragma unroll
      for (int j = 0; j < 4; ++j)
        op[(size_t)(oc + j) * 3136] = acc[g][h][j] + bv[h][j];
    }
  }
}

// ---------------- fallback (ws too small): naive direct conv ----------------
__global__ void conv_naive(const float* __restrict__ x, const float* __restrict__ wt,
                           const float* __restrict__ bias, float* __restrict__ out) {
  const int idx = blockIdx.x * 256 + threadIdx.x;
  if (idx >= NB * CO * 3136) return;
  const int w  = idx % HW_;
  const int h  = (idx / HW_) % HW_;
  const int oc = (idx / 3136) % CO;
  const int nb = idx / (3136 * CO);
  float s = bias[oc];
  for (int c = 0; c < CI; ++c)
    for (int kh = 0; kh < 3; ++kh) {
      const int ih = h + kh - 1;
      if (ih < 0 || ih >= HW_) continue;
      for (int kw = 0; kw < 3; ++kw) {
        const int iw = w + kw - 1;
        if (iw < 0 || iw >= HW_) continue;
        s += x[((size_t)(nb * CI + c) * HW_ + ih) * HW_ + iw] *
             wt[(((size_t)oc * CI + c) * 3 + kh) * 3 + kw];
      }
    }
  out[idx] = s;
}

extern "C" void kernel_launch(void* const* d_in, const int* in_sizes, int n_in,
                              void* d_out, int out_size, void* d_ws, size_t ws_size,
                              hipStream_t stream) {
  const float* x    = (const float*)d_in[0];
  const float* wt   = (const float*)d_in[1];
  const float* bias = (const float*)d_in[2];
  float* out        = (float*)d_out;

  if (ws_size < XP_BYTES + WT_BYTES) {
    conv_naive<<<(NB * CO * 3136 + 255) / 256, 256, 0, stream>>>(x, wt, bias, out);
    return;
  }

  short* xp  = (short*)d_ws;
  short* wbT = (short*)((char*)d_ws + XP_BYTES);

  pad_convert<<<NB * HP, 256, 0, stream>>>(x, xp, wt, wbT);
  conv_gemm<<<(MTOT / 128) * 2, 256, 0, stream>>>(xp, wbT, bias, out);
}

// Round 14
// 95.851 us; speedup vs baseline: 1.0278x; 1.0278x over previous
//
#include <hip/hip_runtime.h>
#include <cstdint>
#include <cstddef>

// ---------------- problem constants ----------------
#define NB    32          // batch
#define CI    128         // in channels
#define CO    256         // out channels
#define HW_   56          // spatial
#define HP    58          // padded spatial
#define KTOT  1152        // 128*9 reduction
#define NKT   36          // K-tiles of 32 (18 bodies of 2)
#define MTOT  (NB * HW_ * HW_)   // 100352 output pixels

static constexpr size_t XP_ELEMS = (size_t)NB * HP * HP * CI;   // 13,776,896
static constexpr size_t WT_ELEMS = (size_t)CO * KTOT;           // 294,912
static constexpr size_t XP_BYTES = XP_ELEMS * 2;
static constexpr size_t WT_BYTES = WT_ELEMS * 2;

typedef __attribute__((ext_vector_type(8))) short bf16x8;
typedef __attribute__((ext_vector_type(4))) float f32x4;

__device__ __forceinline__ short f32_to_bf16(float f) {
  uint32_t u = __float_as_uint(f);
  uint32_t r = (u + 0x7FFFu + ((u >> 16) & 1u)) >> 16;
  return (short)r;
}

typedef __attribute__((address_space(3))) void       lds_void;
typedef const __attribute__((address_space(1))) void gbl_void;

__device__ __forceinline__ void gload16(const void* g, void* l) {
  // dest = wave-uniform LDS base; HW writes lane's 16B at base + lane*16
  __builtin_amdgcn_global_load_lds((gbl_void*)g, (lds_void*)l, 16, 0, 0);
}

// ---- pre-pass: x NCHW f32 -> padded NHWC bf16; wt OIHW -> [o][kh][kw][c] bf16 ----
// (verified-correct R4/R12/R13 version)
__global__ void pad_convert(const float* __restrict__ x, short* __restrict__ xp,
                            const float* __restrict__ wt, short* __restrict__ wbT) {
  __shared__ float lds[CI][57];
  const int blk = blockIdx.x;    // NB*HP = 1856
  const int hp  = blk % HP;
  const int nb  = blk / HP;
  const int tid = threadIdx.x;   // 256

  if (blk < 1152) {              // 1152*256 == WT_ELEMS (scalar per thread)
    int idx = blk * 256 + tid;
    int c  = idx & 127;
    int t  = idx >> 7;          // o*9 + kh*3 + kw
    int kw = t % 3;  int t2 = t / 3;
    int kh = t2 % 3; int o  = t2 / 3;
    wbT[idx] = f32_to_bf16(wt[(((size_t)o * CI + c) * 3 + kh) * 3 + kw]);
  }

  const bool interior = (hp >= 1 && hp <= HW_);
  if (interior) {
    const float* src = x + (size_t)nb * CI * HW_ * HW_ + (size_t)(hp - 1) * HW_;
    for (int t = tid; t < CI * HW_; t += 256) {
      int c = t / HW_, w = t - (t / HW_) * HW_;
      lds[c][w] = src[(size_t)c * HW_ * HW_ + w];
    }
  }
  __syncthreads();
  short* dst = xp + (size_t)(nb * HP + hp) * HP * CI;
  for (int t = tid; t < HP * CI / 4; t += 256) {
    const int wp = t >> 5;
    const int c4 = (t & 31) * 4;
    short4 s;
    if (interior && wp >= 1 && wp <= HW_) {
      s.x = f32_to_bf16(lds[c4 + 0][wp - 1]);
      s.y = f32_to_bf16(lds[c4 + 1][wp - 1]);
      s.z = f32_to_bf16(lds[c4 + 2][wp - 1]);
      s.w = f32_to_bf16(lds[c4 + 3][wp - 1]);
    } else {
      s.x = s.y = s.z = s.w = 0;
    }
    *(short4*)(dst + t * 4) = s;
  }
}

// scalar byte offset into an xp pixel row for K-tile u (tap + channel-quarter)
__device__ __forceinline__ int stage_aoff(int u) {
  const int tap = u >> 2;            // 0..8
  const int cq  = u & 3;             // channel quarter (32 ch)
  const int kh  = tap / 3, kw = tap - kh * 3;
  return ((kh * HP + kw) * CI + cq * 32) * 2;
}

// ---------------- main: implicit GEMM, 128x128 tile, BK=32, 4 waves ----------------
// R14: R13's geometry with HALVED fence count (per-tile-overhead model):
//  * body t computes K-tiles 2t,2t+1 and stages 2t+2,2t+3 AT BODY START;
//    4 x 16KB buffers (tiles rotate mod 4) = 64KB -> 2 blocks/CU.
//  * ONE vmcnt(0)+barrier per body (18 fences, not 36). The drain is cheap:
//    the staged loads were issued a full body (~1400 cyc) earlier >> L2
//    latency, so outstanding ~0 by fence time (m97-style stage-early drain).
//  * WAR safe: body t's stages target bufs (2t+2)%4,(2t+3)%4 = the bufs read
//    in body t-1, whose reads completed before body t-1's end barrier.
//  * swizzle pcs/koff + epilogue verbatim from R4/R13 (0 conflicts, 5 rounds).
__global__ __launch_bounds__(256, 2) void conv_gemm(
    const short* __restrict__ xp, const short* __restrict__ wbT,
    const float* __restrict__ bias, float* __restrict__ out) {
  __shared__ __align__(16) char lds_[4 * 16384];

  const int tid = threadIdx.x;     // 256
  const int l   = tid & 63;
  const int wv  = tid >> 6;        // 0..3
  const int wm  = wv >> 1;         // 0..1  (m half: 64 rows)
  const int wn  = wv & 1;          // 0..1  (oc half: 64 cols)

  // grid 1568 = 8 XCDs x 196; chunked bijective swizzle, nt inner (A L2 reuse)
  const int bid = blockIdx.x;
  const int lin = (bid & 7) * 196 + (bid >> 3);
  const int mt  = lin >> 1;        // 0..783
  const int nt  = lin & 1;

  // ---- staging source pointers (pre-swizzled per rule #21; R4 verbatim) ----
  const int pcs  = (((l & 3) ^ ((l >> 3) & 3)) << 4);
  const int srow = 16 * wv + (l >> 2);                 // 0..63 per gload group
  const char *aSrc0, *aSrc1;
  {
#pragma unroll
    for (int g = 0; g < 2; ++g) {
      int m  = mt * 128 + 64 * g + srow;
      int nb = m / 3136, hw = m - nb * 3136;
      int h = hw / HW_, w = hw - (hw / HW_) * HW_;
      const char* p = (const char*)xp + ((size_t)((nb * HP + h) * HP + w) * CI) * 2 + pcs;
      if (g == 0) aSrc0 = p; else aSrc1 = p;
    }
  }
  const char* bSrc0 = (const char*)wbT + (size_t)(nt * 128 +      srow) * KTOT * 2 + pcs;
  const char* bSrc1 = (const char*)wbT + (size_t)(nt * 128 + 64 + srow) * KTOT * 2 + pcs;

  // ---- frag read lane offsets (swizzled koff; R4 verbatim, 0 conflicts) ----
  const int lm   = l & 15;
  const int koff = (((l >> 4) ^ ((l >> 1) & 3)) << 4);
  const int raOff = (wm * 64 + lm) * 64 + koff;   // + g*1024, g=0..3
  const int rbOff = (wn * 64 + lm) * 64 + koff;   // + h*1024 (B region +8192)

#define STAGE(U, BUF)                                                        \
  {                                                                          \
    const int ao_ = stage_aoff(U);                                           \
    const int bo_ = (U) * 64;                                                \
    gload16(aSrc0 + ao_, (BUF) +         wv * 1024);                         \
    gload16(aSrc1 + ao_, (BUF) +  4096 + wv * 1024);                         \
    gload16(bSrc0 + bo_, (BUF) +  8192 + wv * 1024);                         \
    gload16(bSrc1 + bo_, (BUF) + 12288 + wv * 1024);                         \
  }

// compute one K32 tile from BUF (8 ds_read_b128 + 16 MFMA)
#define COMPUTE(BUF)                                                         \
  {                                                                          \
    bf16x8 af[4], bf[4];                                                     \
    _Pragma("unroll") for (int g = 0; g < 4; ++g)                            \
        af[g] = *(const bf16x8*)((BUF) + raOff + g * 1024);                  \
    _Pragma("unroll") for (int h = 0; h < 4; ++h)                            \
        bf[h] = *(const bf16x8*)((BUF) + 8192 + rbOff + h * 1024);           \
    __builtin_amdgcn_s_setprio(1);                                           \
    _Pragma("unroll") for (int g = 0; g < 4; ++g)                            \
      _Pragma("unroll") for (int h = 0; h < 4; ++h)                          \
        acc[g][h] = __builtin_amdgcn_mfma_f32_16x16x32_bf16(                 \
            bf[h], af[g], acc[g][h], 0, 0, 0);                               \
    __builtin_amdgcn_s_setprio(0);                                           \
  }

  char* buf[4] = { lds_, lds_ + 16384, lds_ + 32768, lds_ + 49152 };

  f32x4 acc[4][4];
#pragma unroll
  for (int g = 0; g < 4; ++g)
#pragma unroll
    for (int h = 0; h < 4; ++h) acc[g][h] = {0.f, 0.f, 0.f, 0.f};

  // ---- prologue: stage tiles 0,1; drain; barrier ----
  STAGE(0, buf[0])
  STAGE(1, buf[1])
  asm volatile("s_waitcnt vmcnt(0)" ::: "memory");
  __builtin_amdgcn_s_barrier();
  __builtin_amdgcn_sched_barrier(0);

// body: stage tiles U+2,U+3 early, compute U,U+1, one fence
#define BODY(U, S0, S1, C0, C1, LAST)                                        \
  {                                                                          \
    if (!(LAST)) { STAGE((U) + 2, S0) STAGE((U) + 3, S1) }                   \
    COMPUTE(C0)                                                              \
    COMPUTE(C1)                                                              \
    asm volatile("s_waitcnt vmcnt(0)" ::: "memory");                         \
    __builtin_amdgcn_s_barrier();                                            \
    __builtin_amdgcn_sched_barrier(0);                                       \
  }

  for (int u = 0; u < NKT; u += 4) {
    BODY(u,     buf[2], buf[3], buf[0], buf[1], false)
    BODY(u + 2, buf[0], buf[1], buf[2], buf[3], (u + 2 == NKT - 2))
  }
#undef BODY
#undef COMPUTE
#undef STAGE

  // ---- epilogue: D rows = oc, cols = m (swapped operands); R13 verbatim ----
  const int mBase = mt * 128 + wm * 64 + lm;
  const int ocB   = nt * 128 + wn * 64 + (l >> 4) * 4;
  float bv[4][4];
#pragma unroll
  for (int h = 0; h < 4; ++h)
#pragma unroll
    for (int j = 0; j < 4; ++j) bv[h][j] = bias[ocB + h * 16 + j];
#pragma unroll
  for (int g = 0; g < 4; ++g) {
    const int m  = mBase + g * 16;
    const int nb = m / 3136;
    const int hw = m - nb * 3136;
    float* op = out + (size_t)nb * CO * 3136 + hw;
#pragma unroll
    for (int h = 0; h < 4; ++h) {
      const int oc = ocB + h * 16;
#pragma unroll
      for (int j = 0; j < 4; ++j)
        op[(size_t)(oc + j) * 3136] = acc[g][h][j] + bv[h][j];
    }
  }
}

// ---------------- fallback (ws too small): naive direct conv ----------------
__global__ void conv_naive(const float* __restrict__ x, const float* __restrict__ wt,
                           const float* __restrict__ bias, float* __restrict__ out) {
  const int idx = blockIdx.x * 256 + threadIdx.x;
  if (idx >= NB * CO * 3136) return;
  const int w  = idx % HW_;
  const int h  = (idx / HW_) % HW_;
  const int oc = (idx / 3136) % CO;
  const int nb = idx / (3136 * CO);
  float s = bias[oc];
  for (int c = 0; c < CI; ++c)
    for (int kh = 0; kh < 3; ++kh) {
      const int ih = h + kh - 1;
      if (ih < 0 || ih >= HW_) continue;
      for (int kw = 0; kw < 3; ++kw) {
        const int iw = w + kw - 1;
        if (iw < 0 || iw >= HW_) continue;
        s += x[((size_t)(nb * CI + c) * HW_ + ih) * HW_ + iw] *
             wt[(((size_t)oc * CI + c) * 3 + kh) * 3 + kw];
      }
    }
  out[idx] = s;
}

extern "C" void kernel_launch(void* const* d_in, const int* in_sizes, int n_in,
                              void* d_out, int out_size, void* d_ws, size_t ws_size,
                              hipStream_t stream) {
  const float* x    = (const float*)d_in[0];
  const float* wt   = (const float*)d_in[1];
  const float* bias = (const float*)d_in[2];
  float* out        = (float*)d_out;

  if (ws_size < XP_BYTES + WT_BYTES) {
    conv_naive<<<(NB * CO * 3136 + 255) / 256, 256, 0, stream>>>(x, wt, bias, out);
    return;
  }

  short* xp  = (short*)d_ws;
  short* wbT = (short*)((char*)d_ws + XP_BYTES);

  pad_convert<<<NB * HP, 256, 0, stream>>>(x, xp, wt, wbT);
  conv_gemm<<<(MTOT / 128) * 2, 256, 0, stream>>>(xp, wbT, bias, out);
}

// Round 15
// 93.562 us; speedup vs baseline: 1.0529x; 1.0245x over previous
//
#include <hip/hip_runtime.h>
#include <cstdint>
#include <cstddef>

// ---------------- problem constants ----------------
#define NB    32          // batch
#define CI    128         // in channels
#define CO    256         // out channels
#define HW_   56          // spatial
#define HP    58          // padded spatial
#define KTOT  1152        // 128*9 reduction
#define NKT   36          // K-tiles of 32
#define MTOT  (NB * HW_ * HW_)   // 100352 output pixels
#define BM    224         // M-tile (14 x 16); 448 M-tiles exactly

static constexpr size_t XP_ELEMS = (size_t)NB * HP * HP * CI;   // 13,776,896
static constexpr size_t WT_ELEMS = (size_t)CO * KTOT;           // 294,912
static constexpr size_t XP_BYTES = XP_ELEMS * 2;
static constexpr size_t WT_BYTES = WT_ELEMS * 2;

typedef __attribute__((ext_vector_type(8))) short bf16x8;
typedef __attribute__((ext_vector_type(4))) float f32x4;

__device__ __forceinline__ short f32_to_bf16(float f) {
  uint32_t u = __float_as_uint(f);
  uint32_t r = (u + 0x7FFFu + ((u >> 16) & 1u)) >> 16;
  return (short)r;
}

typedef __attribute__((address_space(3))) void       lds_void;
typedef const __attribute__((address_space(1))) void gbl_void;

__device__ __forceinline__ void gload16(const void* g, void* l) {
  // dest = wave-uniform LDS base; HW writes lane's 16B at base + lane*16
  __builtin_amdgcn_global_load_lds((gbl_void*)g, (lds_void*)l, 16, 0, 0);
}

// ---- pre-pass: x NCHW f32 -> padded NHWC bf16; wt OIHW -> [o][kh][kw][c] bf16 ----
// (verified-correct R4 version; runs at ~5.8 TB/s effective -> HBM roofline)
__global__ void pad_convert(const float* __restrict__ x, short* __restrict__ xp,
                            const float* __restrict__ wt, short* __restrict__ wbT) {
  __shared__ float lds[CI][57];
  const int blk = blockIdx.x;    // NB*HP = 1856
  const int hp  = blk % HP;
  const int nb  = blk / HP;
  const int tid = threadIdx.x;   // 256

  if (blk < 1152) {              // 1152*256 == WT_ELEMS (scalar per thread)
    int idx = blk * 256 + tid;
    int c  = idx & 127;
    int t  = idx >> 7;          // o*9 + kh*3 + kw
    int kw = t % 3;  int t2 = t / 3;
    int kh = t2 % 3; int o  = t2 / 3;
    wbT[idx] = f32_to_bf16(wt[(((size_t)o * CI + c) * 3 + kh) * 3 + kw]);
  }

  const bool interior = (hp >= 1 && hp <= HW_);
  if (interior) {
    const float* src = x + (size_t)nb * CI * HW_ * HW_ + (size_t)(hp - 1) * HW_;
    for (int t = tid; t < CI * HW_; t += 256) {
      int c = t / HW_, w = t - (t / HW_) * HW_;
      lds[c][w] = src[(size_t)c * HW_ * HW_ + w];
    }
  }
  __syncthreads();
  short* dst = xp + (size_t)(nb * HP + hp) * HP * CI;
  for (int t = tid; t < HP * CI / 4; t += 256) {
    const int wp = t >> 5;
    const int c4 = (t & 31) * 4;
    short4 s;
    if (interior && wp >= 1 && wp <= HW_) {
      s.x = f32_to_bf16(lds[c4 + 0][wp - 1]);
      s.y = f32_to_bf16(lds[c4 + 1][wp - 1]);
      s.z = f32_to_bf16(lds[c4 + 2][wp - 1]);
      s.w = f32_to_bf16(lds[c4 + 3][wp - 1]);
    } else {
      s.x = s.y = s.z = s.w = 0;
    }
    *(short4*)(dst + t * 4) = s;
  }
}

// scalar byte offset into an xp pixel row for K-tile u (tap + channel-quarter)
__device__ __forceinline__ int stage_aoff(int u) {
  const int tap = u >> 2;            // 0..8
  const int cq  = u & 3;             // channel quarter (32 ch)
  const int kh  = tap / 3, kw = tap - kh * 3;
  return ((kh * HP + kw) * CI + cq * 32) * 2;
}

// ---------------- main: implicit GEMM, 224x128 tile, BK=32, 4 waves ----------------
// FINAL (best-measured, R12): R4's proven structure (counted vmcnt(6),
// 3 x 24KB buffers, 2 blocks/CU, zero-conflict both-sides swizzle) with
// BM=224 to balance the scheduling tail (grid 896 / 512 slots = 1.75 rounds,
// eff 0.875). Session findings: 11 structural variants (fences, occupancy,
// tile geometry, fine-phasing, B-direct) all land at 29-31% MfmaUtil /
// 723-770 TF -- the 2-barrier m97-class structure's balanced-pipe plateau
// at this conv shape (MFMA ~620 + LDS ~290 + VALU ~320 cyc per SIMD per
// tile-pair). Escaping it requires the co-designed 8-phase stack, which
// raced/regressed in 3 attempts (consistent with learn_hip m152/m232).
__global__ __launch_bounds__(256, 2) void conv_gemm(
    const short* __restrict__ xp, const short* __restrict__ wbT,
    const float* __restrict__ bias, float* __restrict__ out) {
  __shared__ __align__(16) char lds_[3 * 24576];

  const int tid = threadIdx.x;     // 256
  const int l   = tid & 63;
  const int wv  = tid >> 6;        // 0..3
  const int wm  = wv >> 1;         // 0..1  (m half: 112 rows)
  const int wn  = wv & 1;          // 0..1  (oc half: 64 cols)

  // grid 896 = 8 XCDs x 112; chunked bijective swizzle, nt inner (A reuse in L2)
  const int bid = blockIdx.x;
  const int lin = (bid & 7) * 112 + (bid >> 3);
  const int mt  = lin >> 1;        // 0..447
  const int nt  = lin & 1;

  // ---- staging source pointers (pre-swizzled per rule #21) ----
  // gload g covers rows 64g + 16wv + (l>>2); lane piece (l&3); src piece ^((l>>3)&3)
  const int pcs  = (((l & 3) ^ ((l >> 3) & 3)) << 4);
  const int srow = 16 * wv + (l >> 2);                 // 0..63 per gload group
  const char *aSrc0, *aSrc1, *aSrc2, *aSrc3;
  {
#pragma unroll
    for (int g = 0; g < 4; ++g) {
      int m  = mt * BM + 64 * g + srow;
      if (m >= MTOT) m = 0;            // clamp: garbage rows 224-255, never read
      int nb = m / 3136, hw = m - nb * 3136;
      int h = hw / HW_, w = hw - (hw / HW_) * HW_;
      const char* p = (const char*)xp + ((size_t)((nb * HP + h) * HP + w) * CI) * 2 + pcs;
      if (g == 0) aSrc0 = p; else if (g == 1) aSrc1 = p;
      else if (g == 2) aSrc2 = p; else aSrc3 = p;
    }
  }
  const char* bSrc0 = (const char*)wbT + (size_t)(nt * 128 +      srow) * KTOT * 2 + pcs;
  const char* bSrc1 = (const char*)wbT + (size_t)(nt * 128 + 64 + srow) * KTOT * 2 + pcs;

  // ---- frag read lane offsets (swizzled koff; 0 conflicts, 6 passing rounds) ----
  const int lm   = l & 15;
  const int koff = (((l >> 4) ^ ((l >> 1) & 3)) << 4);
  const int raOff = (wm * 112 + lm) * 64 + koff;   // + g*1024, g=0..6
  const int rbOff = (wn * 64 + lm) * 64 + koff;    // + h*1024 (B region +16384)

  char* B0 = lds_;
  char* B1 = lds_ + 24576;
  char* B2 = lds_ + 49152;

#define STAGE(U, BUF)                                                        \
  {                                                                          \
    const int ao_ = stage_aoff(U);                                           \
    const int bo_ = (U) * 64;                                                \
    gload16(aSrc0 + ao_, (BUF) +         wv * 1024);                         \
    gload16(aSrc1 + ao_, (BUF) +  4096 + wv * 1024);                         \
    gload16(aSrc2 + ao_, (BUF) +  8192 + wv * 1024);                         \
    gload16(aSrc3 + ao_, (BUF) + 12288 + wv * 1024);                         \
    gload16(bSrc0 + bo_, (BUF) + 16384 + wv * 1024);                         \
    gload16(bSrc1 + bo_, (BUF) + 20480 + wv * 1024);                         \
  }

  f32x4 acc[7][4];
#pragma unroll
  for (int g = 0; g < 7; ++g)
#pragma unroll
    for (int h = 0; h < 4; ++h) acc[g][h] = {0.f, 0.f, 0.f, 0.f};

  // ---- prologue: stage tiles 0,1; confirm tile 0 ----
  STAGE(0, B0)
  STAGE(1, B1)
  asm volatile("s_waitcnt vmcnt(6)" ::: "memory");   // tile 0 landed
  __builtin_amdgcn_s_barrier();
  __builtin_amdgcn_sched_barrier(0);

#define TILE_BODY(V, CUR, STG)                                               \
  {                                                                          \
    const int v_ = (V);                                                      \
    if (v_ + 2 < NKT) STAGE(v_ + 2, STG)                                     \
    bf16x8 af[7], bf[4];                                                     \
    _Pragma("unroll") for (int g = 0; g < 7; ++g)                            \
        af[g] = *(const bf16x8*)((CUR) + raOff + g * 1024);                  \
    _Pragma("unroll") for (int h = 0; h < 4; ++h)                            \
        bf[h] = *(const bf16x8*)((CUR) + 16384 + rbOff + h * 1024);          \
    __builtin_amdgcn_s_setprio(1);                                           \
    _Pragma("unroll") for (int g = 0; g < 7; ++g)                            \
      _Pragma("unroll") for (int h = 0; h < 4; ++h)                          \
        acc[g][h] = __builtin_amdgcn_mfma_f32_16x16x32_bf16(                 \
            bf[h], af[g], acc[g][h], 0, 0, 0);                               \
    __builtin_amdgcn_s_setprio(0);                                           \
    if (v_ < NKT - 1) {                                                      \
      if (v_ == NKT - 2) { asm volatile("s_waitcnt vmcnt(0)" ::: "memory"); }\
      else               { asm volatile("s_waitcnt vmcnt(6)" ::: "memory"); }\
      __builtin_amdgcn_s_barrier();                                          \
      __builtin_amdgcn_sched_barrier(0);                                     \
    }                                                                        \
  }

  for (int v3 = 0; v3 < NKT; v3 += 3) {
    TILE_BODY(v3 + 0, B0, B2)   // tile v reads buf v%3, stages v+2 into (v+2)%3
    TILE_BODY(v3 + 1, B1, B0)
    TILE_BODY(v3 + 2, B2, B1)
  }
#undef TILE_BODY
#undef STAGE

  // ---- epilogue: D rows = oc, cols = m (swapped operands) -> coalesced stores ----
  const int mBase = mt * BM + wm * 112 + lm;
  const int ocB   = nt * 128 + wn * 64 + (l >> 4) * 4;
  float bv[4][4];
#pragma unroll
  for (int h = 0; h < 4; ++h)
#pragma unroll
    for (int j = 0; j < 4; ++j) bv[h][j] = bias[ocB + h * 16 + j];
#pragma unroll
  for (int g = 0; g < 7; ++g) {
    const int m  = mBase + g * 16;
    const int nb = m / 3136;
    const int hw = m - nb * 3136;
    float* op = out + (size_t)nb * CO * 3136 + hw;
#pragma unroll
    for (int h = 0; h < 4; ++h) {
      const int oc = ocB + h * 16;
#pragma unroll
      for (int j = 0; j < 4; ++j)
        op[(size_t)(oc + j) * 3136] = acc[g][h][j] + bv[h][j];
    }
  }
}

// ---------------- fallback (ws too small): naive direct conv ----------------
__global__ void conv_naive(const float* __restrict__ x, const float* __restrict__ wt,
                           const float* __restrict__ bias, float* __restrict__ out) {
  const int idx = blockIdx.x * 256 + threadIdx.x;
  if (idx >= NB * CO * 3136) return;
  const int w  = idx % HW_;
  const int h  = (idx / HW_) % HW_;
  const int oc = (idx / 3136) % CO;
  const int nb = idx / (3136 * CO);
  float s = bias[oc];
  for (int c = 0; c < CI; ++c)
    for (int kh = 0; kh < 3; ++kh) {
      const int ih = h + kh - 1;
      if (ih < 0 || ih >= HW_) continue;
      for (int kw = 0; kw < 3; ++kw) {
        const int iw = w + kw - 1;
        if (iw < 0 || iw >= HW_) continue;
        s += x[((size_t)(nb * CI + c) * HW_ + ih) * HW_ + iw] *
             wt[(((size_t)oc * CI + c) * 3 + kh) * 3 + kw];
      }
    }
  out[idx] = s;
}

extern "C" void kernel_launch(void* const* d_in, const int* in_sizes, int n_in,
                              void* d_out, int out_size, void* d_ws, size_t ws_size,
                              hipStream_t stream) {
  const float* x    = (const float*)d_in[0];
  const float* wt   = (const float*)d_in[1];
  const float* bias = (const float*)d_in[2];
  float* out        = (float*)d_out;

  if (ws_size < XP_BYTES + WT_BYTES) {
    conv_naive<<<(NB * CO * 3136 + 255) / 256, 256, 0, stream>>>(x, wt, bias, out);
    return;
  }

  short* xp  = (short*)d_ws;
  short* wbT = (short*)((char*)d_ws + XP_BYTES);

  pad_convert<<<NB * HP, 256, 0, stream>>>(x, xp, wt, wbT);
  conv_gemm<<<(MTOT / BM) * 2, 256, 0, stream>>>(xp, wbT, bias, out);
}